// Round 18
// baseline (448.380 us; speedup 1.0000x reference)
//
#include <hip/hip_runtime.h>
#include <hip/hip_bf16.h>
#include <math.h>

typedef unsigned short u16;
typedef short s16x8 __attribute__((ext_vector_type(8)));
typedef float f32x4v __attribute__((ext_vector_type(4)));
typedef int i32x4 __attribute__((ext_vector_type(4)));
typedef unsigned short u16x4 __attribute__((ext_vector_type(4)));

#define EDIM 300
#define EPAD 320
#define VOCAB 50000

// ---- fixed workspace layout (bytes) ----
static constexpr size_t SZ_WIH  = (size_t)2 * 1024 * EPAD * 2;   // bf16 [2][1024 pack][320]
static constexpr size_t SZ_WPK  = (size_t)2 * 1024 * 256;        // i8 packed Whh frags
static constexpr size_t SZ_SW   = (size_t)2 * 1024 * 4;          // f32 per-row scale (pack order)
static constexpr size_t SZ_BIAS = (size_t)2 * 1024 * 4;          // f32 (pack order)
static constexpr size_t SZ_HSV  = (size_t)2 * 256 * 256;         // i8 h chunk-boundary save
static constexpr size_t SZ_CST  = (size_t)2 * 256 * 256 * 4;     // f32 c-state
static constexpr size_t SZ_VAC  = (size_t)2 * 256 * 256 * 4;     // f32 vacc-state
static constexpr size_t SZ_VOUT = (size_t)2 * 128 * 512 * 4;     // f32 [2][128][512]
static constexpr size_t SZ_EMB  = (size_t)VOCAB * EPAD * 2;      // bf16 emb table padded (32 MB)
static constexpr size_t SZ_PAD  = (size_t)512 * 1024;            // shared overrun pad after slab1
static constexpr size_t FIXED_B = SZ_WIH + SZ_WPK + SZ_SW + SZ_BIAS + SZ_HSV + SZ_CST + SZ_VAC + SZ_VOUT + SZ_EMB + SZ_PAD;
static constexpr size_t SZ_STEP = (size_t)2 * 256 * 1024 * 2;    // ginc bytes per timestep (1 MB, both dirs)

// pack permutation: pack p = w*128 + q*16 + ul  (w=wave 0..7, q=uh*4+gate, ul 0..15)
//   -> logical Whh/Wih row jlog = (q&3)*256 + w*32 + (q>>2)*16 + ul
// sigma (ginc column) s = w*128 + uh*64 + ul*4 + gate  (gates contiguous per cell)

__device__ __forceinline__ float bf2f(u16 u) {
  union { float f; unsigned int i; } v; v.i = ((unsigned int)u) << 16; return v.f;
}
__device__ __forceinline__ u16 f2bf(float f) {
  union { float f; unsigned int i; } v; v.f = f;
  unsigned int r = v.i + 0x7fffu + ((v.i >> 16) & 1u);   // RNE (finite inputs)
  return (u16)(r >> 16);
}
__device__ __forceinline__ void gload_lds16(const void* g, void* l) {
  __builtin_amdgcn_global_load_lds((const __attribute__((address_space(1))) void*)g,
                                   (__attribute__((address_space(3))) void*)l, 16, 0, 0);
}
// order LDS ops across waves WITHOUT draining vmcnt
__device__ __forceinline__ void lds_barrier() {
  asm volatile("s_waitcnt lgkmcnt(0)" ::: "memory");
  __builtin_amdgcn_s_barrier();
}
// intra-wave LDS exchange fence (R13 bug fix): pins write->read order vs compiler AA
__device__ __forceinline__ void wave_lds_fence() {
  asm volatile("s_waitcnt lgkmcnt(0)" ::: "memory");
  __builtin_amdgcn_sched_barrier(0);
}

// ---------------- prep: Wih->bf16 padded (pack-row order), bias sum (pack order) ----------------
__global__ void prep_kernel(const float* wih_f, const float* bih_f, const float* bhh_f,
                            const float* wih_b, const float* bih_b, const float* bhh_b,
                            u16* wih_bf, float* bias)
{
  int tid = blockIdx.x * blockDim.x + threadIdx.x;
  if (tid < 2 * 1024 * EPAD) {
    int d = tid / (1024 * EPAD); int rr = tid % (1024 * EPAD);
    int p = rr / EPAD; int k = rr % EPAD;
    int w = p >> 7, q = (p >> 4) & 7, ul = p & 15;
    int jlog = (q & 3) * 256 + w * 32 + (q >> 2) * 16 + ul;
    const float* wsrc = d ? wih_b : wih_f;
    wih_bf[tid] = (k < EDIM) ? f2bf(wsrc[(size_t)jlog * EDIM + k]) : (u16)0;
  }
  int t2 = tid - 2 * 1024 * EPAD;
  if (t2 >= 0 && t2 < 2 * 1024) {
    int d = t2 >> 10; int p = t2 & 1023;
    int w = p >> 7, q = (p >> 4) & 7, ul = p & 15;
    int jlog = (q & 3) * 256 + w * 32 + (q >> 2) * 16 + ul;
    bias[t2] = d ? (bih_b[jlog] + bhh_b[jlog]) : (bih_f[jlog] + bhh_f[jlog]);
  }
}

// ---------------- emb -> bf16, K padded 300->320 (one-time) ----------------
__global__ void embconv_kernel(const float* emb, u16* embbf)
{
  int r = blockIdx.x;
  int k = threadIdx.x;     // 320
  embbf[(size_t)r * EPAD + k] = (k < EDIM) ? f2bf(emb[(size_t)r * EDIM + k]) : (u16)0;
}

// ---------------- Whh -> i8 quant + MFMA-fragment pack (8-wave pack order) ----------------
__global__ void whhq_kernel(const float* whh_f, const float* whh_b, char* wpk, float* sw)
{
  int jp = blockIdx.x;             // 0..2047 = d*1024 + pack p
  int t = threadIdx.x;             // 64
  int d = jp >> 10, p = jp & 1023;
  int w = p >> 7, q = (p >> 4) & 7, ul = p & 15;
  int jlog = (q & 3) * 256 + w * 32 + (q >> 2) * 16 + ul;
  const float* src = (d ? whh_b : whh_f) + (size_t)jlog * 256;
  float v[4]; float m = 0.f;
  #pragma unroll
  for (int kk = 0; kk < 4; ++kk) { v[kk] = src[t * 4 + kk]; m = fmaxf(m, fabsf(v[kk])); }
  #pragma unroll
  for (int off = 32; off > 0; off >>= 1) m = fmaxf(m, __shfl_xor(m, off));
  float sunit = m / 127.f;
  if (sunit < 1e-30f) sunit = 1e-30f;
  unsigned int pk = 0;
  #pragma unroll
  for (int kk = 0; kk < 4; ++kk) {
    int qv = (int)rintf(v[kk] / sunit);
    qv = qv > 127 ? 127 : (qv < -127 ? -127 : qv);
    pk |= ((unsigned int)(qv & 255)) << (8 * kk);
  }
  size_t base = ((((size_t)(d * 8 + w) * 8 + q) * 4 + (t >> 4)) * 64
                 + (((t >> 2) & 3) * 16 + ul)) * 16 + (t & 3) * 4;
  *(unsigned int*)&wpk[base] = pk;
  if (t == 0) sw[jp] = sunit / 127.f;
}

// ---------------- gemm body: fused gather + input projection, A in REGISTERS ----------------
__device__ __forceinline__ void gemm_body(
    int bid, const int* __restrict__ x1, const int* __restrict__ x2,
    const u16* __restrict__ embbf, const u16* __restrict__ wih_bf,
    const float* __restrict__ bias, u16* __restrict__ slab,
    int t0, int T, int logT, char* smem)
{
  u16* Bs = (u16*)smem;                       // 2 x 16 KB
  int d  = bid >> (1 + logT);
  int tl = (bid >> 1) & (T - 1);
  int R0 = (bid & 1) * 128;
  int lane = threadIdx.x & 63;
  int w = threadIdx.x >> 6;                   // 8 waves; wave rows = w*16..+16

  const int* x = (R0 >> 7) ? x2 : x1;
  int t = t0 + tl;
  int tpos = d ? (255 - t) : t;

  // A -> registers: row (lane&15) of wave tile, k-seg (lane>>4)*8 per kc32 block
  int rowR = R0 + w * 16 + (lane & 15);
  int tok = x[(rowR & 127) * 256 + tpos];
  const char* arow = (const char*)embbf + (size_t)tok * 640 + (lane >> 4) * 16;
  s16x8 areg[10];
  #pragma unroll
  for (int kc = 0; kc < 10; ++kc)
    areg[kc] = *(const s16x8*)(arow + kc * 64);

  const char* Bbase = (const char*)(wih_bf + (size_t)d * 1024 * EPAD);
  int ar  = lane >> 3;
  int acb = (lane & 7) * 16;
  int swz = ar << 4;

  // prologue: stage B(nt=0, kt=0) -> buf0
  #pragma unroll
  for (int i = 0; i < 2; ++i) {
    int lrow = (i * 8 + w) * 8 + ar;
    gload_lds16(Bbase + (size_t)lrow * 640 + (acb ^ swz),
                (char*)Bs + (i * 8 + w) * 1024);
  }
  __syncthreads();

  size_t rowbase = (size_t)(d * T + tl) * 256 + R0;
  int buf = 0;
  int ul = lane & 15;

  for (int nt = 0; nt < 8; ++nt) {
    f32x4v acc[8] = {};
    #pragma unroll
    for (int kt = 0; kt < 5; ++kt) {
      int nkt = kt + 1, nnt = nt;
      if (nkt == 5) { nkt = 0; nnt = nt + 1; }
      if (nnt < 8) {
        #pragma unroll
        for (int i = 0; i < 2; ++i) {
          int lrow = (i * 8 + w) * 8 + ar;
          gload_lds16(Bbase + (size_t)(nnt * 128 + lrow) * 640 + nkt * 128 + (acb ^ swz),
                      (char*)Bs + (buf ^ 1) * 16384 + (i * 8 + w) * 1024);
        }
      }
      #pragma unroll
      for (int kc2 = 0; kc2 < 2; ++kc2) {
        int cb = kc2 * 64 + (lane >> 4) * 16;
        #pragma unroll
        for (int nf = 0; nf < 8; ++nf) {
          int rr = nf * 16 + (lane & 15);
          s16x8 b = *(const s16x8*)((const char*)Bs + buf * 16384 + rr * 128 + (cb ^ ((rr & 7) << 4)));
          acc[nf] = __builtin_amdgcn_mfma_f32_16x16x32_bf16(areg[kt * 2 + kc2], b, acc[nf], 0, 0, 0);
        }
      }
      __syncthreads();
      buf ^= 1;
    }
    // epilogue nt: bias + sigma store (u16x4 = 4 gates of one cell); nf = uh*4+gate
    float bv[8];
    #pragma unroll
    for (int nf = 0; nf < 8; ++nf)
      bv[nf] = bias[d * 1024 + nt * 128 + nf * 16 + ul];
    #pragma unroll
    for (int uh = 0; uh < 2; ++uh)
      #pragma unroll
      for (int i = 0; i < 4; ++i) {
        int row = w * 16 + (lane >> 4) * 4 + i;
        u16x4 v;
        #pragma unroll
        for (int g = 0; g < 4; ++g)
          v[g] = f2bf(acc[uh * 4 + g][i] + bv[uh * 4 + g]);
        *(u16x4*)(slab + (rowbase + row) * 1024 + nt * 128 + uh * 64 + ul * 4) = v;
      }
  }
}

// ---------------- lstm body: R14 structure (all-lane gates, fenced exchange) ----------------
__device__ __forceinline__ void lstm_body(
    int bid, const u16* __restrict__ slab, const i32x4* __restrict__ wpk,
    const float* __restrict__ sw, char* hsave,
    float* cstate, float* vaccst, float* vout,
    const int* __restrict__ len1, const int* __restrict__ len2,
    int t0, int T, char* smem)
{
  char* h = smem;                              // [2 par][2 row][288]
  int* gst = (int*)(smem + 1152);              // [8 wave][64 cell][4 gate]

  const int d = bid >> 7, bt = bid & 127;
  const int tid = threadIdx.x;
  const int lane = tid & 63, w = tid >> 6;
  const int cl = lane & 15;
  const int cr  = lane >> 5;
  const int cuh = (lane >> 4) & 1;
  const int cu  = w * 32 + cuh * 16 + cl;

  i32x4 bfr[8][4];
  #pragma unroll
  for (int q = 0; q < 8; ++q)
    #pragma unroll
    for (int kc = 0; kc < 4; ++kc)
      bfr[q][kc] = wpk[(((size_t)(d * 8 + w) * 8 + q) * 4 + kc) * 64 + lane];
  float swl4[4];
  #pragma unroll
  for (int g = 0; g < 4; ++g)
    swl4[g] = sw[d * 1024 + w * 128 + (cuh * 4 + g) * 16 + cl];

  const int R0 = bt * 2;
  {
    int r = tid >> 8, u = tid & 255;
    h[r * 288 + u] = (t0 > 0) ? hsave[((size_t)d * 256 + R0 + r) * 256 + u] : (char)0;
  }

  const int RR = R0 + cr;
  const int lm = ((RR >> 7) ? len2 : len1)[RR & 127] - 1;
  const size_t sidx = ((size_t)d * 256 + RR) * 256 + cu;
  float c = 0.f, va = 0.f;
  if (t0 > 0) { c = cstate[sidx]; va = vaccst[sidx]; }

  const size_t GSTEP = (size_t)256 * 1024;
  const u16* gcell = slab + ((size_t)d * T * 256 + RR) * 1024 + w * 128 + cuh * 64 + cl * 4;
  u16x4 gv = *(const u16x4*)gcell;
  __syncthreads();

  const bool final_chunk = (t0 + T == 256);
  int par = 0;

  for (int tl = 0; tl < T; ++tl) {
    u16x4 gvn = *(const u16x4*)(gcell + GSTEP * (size_t)(tl + 1));

    // A-frags: mask is (cl<2) only — rows live in lanes {0,1,16,17,32,33,48,49}
    i32x4 a[4] = {{0,0,0,0},{0,0,0,0},{0,0,0,0},{0,0,0,0}};
    if (cl < 2) {
      #pragma unroll
      for (int kc = 0; kc < 4; ++kc)
        a[kc] = *(const i32x4*)&h[(par * 2 + cl) * 288 + kc * 64 + (lane >> 4) * 16];
    }
    i32x4 acc[8];
    #pragma unroll
    for (int q = 0; q < 8; ++q) {
      i32x4 z = {0, 0, 0, 0};
      #pragma unroll
      for (int kc = 0; kc < 4; ++kc)
        z = __builtin_amdgcn_mfma_i32_16x16x64_i8(a[kc], bfr[q][kc], z, 0, 0, 0);
      acc[q] = z;
    }

    if (lane < 16) {
      #pragma unroll
      for (int r2 = 0; r2 < 2; ++r2)
        #pragma unroll
        for (int uh2 = 0; uh2 < 2; ++uh2) {
          i32x4 v = { acc[uh2 * 4 + 0][r2], acc[uh2 * 4 + 1][r2],
                      acc[uh2 * 4 + 2][r2], acc[uh2 * 4 + 3][r2] };
          *(i32x4*)&gst[(w * 64 + r2 * 32 + uh2 * 16 + lane) * 4] = v;
        }
    }
    wave_lds_fence();   // required: compiler may hoist cross-lane read (R13 bug)
    i32x4 g4 = *(const i32x4*)&gst[(w * 64 + lane) * 4];

    {
      float s0 = (float)g4[0] * swl4[0] + bf2f(gv[0]);
      float s1 = (float)g4[1] * swl4[1] + bf2f(gv[1]);
      float s2 = (float)g4[2] * swl4[2] + bf2f(gv[2]);
      float s3 = (float)g4[3] * swl4[3] + bf2f(gv[3]);
      float I = __builtin_amdgcn_rcpf(1.f + __expf(-s0));
      float F = __builtin_amdgcn_rcpf(1.f + __expf(-s1));
      float G = 1.f - 2.f * __builtin_amdgcn_rcpf(__expf(2.f * s2) + 1.f);
      float O = __builtin_amdgcn_rcpf(1.f + __expf(-s3));
      float cn = F * c + I * G;
      c = cn;
      float hn = O * (1.f - 2.f * __builtin_amdgcn_rcpf(__expf(2.f * cn) + 1.f));
      int tmap = d ? (255 - (t0 + tl)) : (t0 + tl);
      if (tmap < lm) va += hn;
      h[((par ^ 1) * 2 + cr) * 288 + cu] = (char)(int)rintf(hn * 127.f);
    }
    lds_barrier();
    gv = gvn;
    par ^= 1;
  }

  cstate[sidx] = c;
  vaccst[sidx] = va;
  if (final_chunk) {
    vout[((size_t)(RR >> 7) * 128 + (RR & 127)) * 512 + d * 256 + cu] = va / (float)lm;
  } else {
    int r = tid >> 8, u = tid & 255;
    hsave[((size_t)d * 256 + R0 + r) * 256 + u] = h[(par * 2 + r) * 288 + u];
  }
}

// ---------------- fused kernel: blocks [0,nL) = lstm(chunk k), rest = gemm(chunk k+1) ----------------
// Zero inter-group dependency (gemm writes the OTHER ginc slab) -> pure co-scheduling.
// __launch_bounds__(512, 2): 2 blocks/CU -> 128 VGPR cap; both bodies fit (R16: (512,4)
// produced a 64-VGPR cap -> catastrophic spills).
__global__ void __launch_bounds__(512, 2)
fused_kernel(const int* x1, const int* x2, const u16* embbf, const u16* wih_bf,
             const float* bias, const i32x4* wpk, const float* sw,
             char* hsave, float* cstate, float* vaccst, float* vout,
             const int* len1, const int* len2,
             const u16* lstm_slab, u16* gemm_slab,
             int lstm_t0, int gemm_t0, int nL, int T, int logT)
{
  __shared__ __align__(16) char smem[32768];
  if ((int)blockIdx.x < nL) {
    lstm_body(blockIdx.x, lstm_slab, wpk, sw, hsave, cstate, vaccst, vout,
              len1, len2, lstm_t0, T, smem);
  } else if (gemm_t0 >= 0) {
    gemm_body(blockIdx.x - nL, x1, x2, embbf, wih_bf, bias, gemm_slab,
              gemm_t0, T, logT, smem);
  }
}

// ---------------- MLP head ----------------
__global__ void mlp_kernel(const float* v, const float* W1, const float* b1,
                           const float* W2, const float* b2, const float* Wo, const float* bo,
                           float* out)
{
  __shared__ float vec[512];
  __shared__ float a1[512];
  __shared__ float red[4];
  int b = blockIdx.x;
  int tid = threadIdx.x;   // 256
  for (int i = tid; i < 512; i += 256)
    vec[i] = fabsf(v[(size_t)b * 512 + i] - v[(size_t)(128 + b) * 512 + i]);
  __syncthreads();
  for (int j = tid; j < 512; j += 256) {
    float s = b1[j];
    const float* wr = W1 + (size_t)j * 512;
    for (int k = 0; k < 512; ++k) s += vec[k] * wr[k];
    a1[j] = fmaxf(s, 0.f);
  }
  __syncthreads();
  float s = b2[tid];
  {
    const float* wr = W2 + (size_t)tid * 512;
    for (int k = 0; k < 512; ++k) s += a1[k] * wr[k];
  }
  float p = fmaxf(s, 0.f) * Wo[tid];
  for (int off = 32; off > 0; off >>= 1) p += __shfl_down(p, off);
  if ((tid & 63) == 0) red[tid >> 6] = p;
  __syncthreads();
  if (tid == 0) {
    float logit = red[0] + red[1] + red[2] + red[3] + bo[0];
    out[b] = logit;
    out[128 + b] = 1.f / (1.f + __expf(-logit));
  }
}

extern "C" void kernel_launch(void* const* d_in, const int* in_sizes, int n_in,
                              void* d_out, int out_size, void* d_ws, size_t ws_size,
                              hipStream_t stream)
{
  const int*   x1    = (const int*)d_in[0];
  const int*   x2    = (const int*)d_in[1];
  const int*   len1  = (const int*)d_in[2];
  const int*   len2  = (const int*)d_in[3];
  const float* emb   = (const float*)d_in[4];
  const float* wih_f = (const float*)d_in[5];
  const float* whh_f = (const float*)d_in[6];
  const float* bih_f = (const float*)d_in[7];
  const float* bhh_f = (const float*)d_in[8];
  const float* wih_b = (const float*)d_in[9];
  const float* whh_b = (const float*)d_in[10];
  const float* bih_b = (const float*)d_in[11];
  const float* bhh_b = (const float*)d_in[12];
  const float* W1    = (const float*)d_in[13];
  const float* b1    = (const float*)d_in[14];
  const float* W2    = (const float*)d_in[15];
  const float* b2    = (const float*)d_in[16];
  const float* Wo    = (const float*)d_in[17];
  const float* bo    = (const float*)d_in[18];

  char* p = (char*)d_ws;
  u16*   wih_bf = (u16*)p;          p += SZ_WIH;
  char*  wpk    = (char*)p;         p += SZ_WPK;
  float* swp    = (float*)p;        p += SZ_SW;
  float* bias   = (float*)p;        p += SZ_BIAS;
  char*  hsave  = (char*)p;         p += SZ_HSV;
  float* cst    = (float*)p;        p += SZ_CST;
  float* vac    = (float*)p;        p += SZ_VAC;
  float* vout   = (float*)p;        p += SZ_VOUT;
  u16*   embbf  = (u16*)p;          p += SZ_EMB;

  // chunk T: prefer 64 (deep pipeline, 512-block fused launches = 1 lstm + 1 gemm per CU);
  // shrink further only if workspace demands.
  int T = 64;
  while (T > 1 && FIXED_B + (size_t)2 * T * SZ_STEP > ws_size) T >>= 1;
  int logT = __builtin_ctz((unsigned)T);
  u16* slab0 = (u16*)p;             p += (size_t)T * SZ_STEP;
  u16* slab1 = (u16*)p;
  u16* slabs[2] = { slab0, slab1 };

  {
    int total = 2 * 1024 * EPAD + 2 * 1024;
    prep_kernel<<<(total + 255) / 256, 256, 0, stream>>>(
        wih_f, bih_f, bhh_f, wih_b, bih_b, bhh_b, wih_bf, bias);
  }
  whhq_kernel<<<2048, 64, 0, stream>>>(whh_f, whh_b, wpk, swp);
  embconv_kernel<<<VOCAB, EPAD, 0, stream>>>(emb, embbf);

  int NCH = 256 / T;
  // pipeline: gemm(0); { lstm(ch-1) || gemm(ch) }; lstm(NCH-1)
  fused_kernel<<<4 * T, 512, 0, stream>>>(x1, x2, embbf, wih_bf, bias,
                                          (const i32x4*)wpk, swp, hsave, cst, vac, vout,
                                          len1, len2, slabs[0], slabs[0],
                                          -1, 0, 0, T, logT);
  for (int ch = 1; ch < NCH; ++ch) {
    fused_kernel<<<256 + 4 * T, 512, 0, stream>>>(x1, x2, embbf, wih_bf, bias,
                                                  (const i32x4*)wpk, swp, hsave, cst, vac, vout,
                                                  len1, len2, slabs[(ch - 1) & 1], slabs[ch & 1],
                                                  (ch - 1) * T, ch * T, 256, T, logT);
  }
  fused_kernel<<<256, 512, 0, stream>>>(x1, x2, embbf, wih_bf, bias,
                                        (const i32x4*)wpk, swp, hsave, cst, vac, vout,
                                        len1, len2, slabs[(NCH - 1) & 1], slabs[0],
                                        (NCH - 1) * T, -1, 256, T, logT);

  mlp_kernel<<<128, 256, 0, stream>>>(vout, W1, b1, W2, b2, Wo, bo, (float*)d_out);
}

// Round 19
// 442.923 us; speedup vs baseline: 1.0123x; 1.0123x over previous
//
#include <hip/hip_runtime.h>
#include <hip/hip_bf16.h>
#include <math.h>

typedef unsigned short u16;
typedef short s16x8 __attribute__((ext_vector_type(8)));
typedef float f32x4v __attribute__((ext_vector_type(4)));
typedef int i32x4 __attribute__((ext_vector_type(4)));
typedef unsigned short u16x4 __attribute__((ext_vector_type(4)));

#define EDIM 300
#define EPAD 320
#define VOCAB 50000

// ---- fixed workspace layout (bytes) ----
static constexpr size_t SZ_WIH  = (size_t)2 * 1024 * EPAD * 2;   // bf16 [2][1024 pack][320]
static constexpr size_t SZ_WPK  = (size_t)2 * 1024 * 256;        // i8 packed Whh frags
static constexpr size_t SZ_SW   = (size_t)2 * 1024 * 4;          // f32 per-row scale (pack order)
static constexpr size_t SZ_BIAS = (size_t)2 * 1024 * 4;          // f32 (pack order)
static constexpr size_t SZ_HSV  = (size_t)2 * 256 * 256;         // i8 h chunk-boundary save
static constexpr size_t SZ_CST  = (size_t)2 * 256 * 256 * 4;     // f32 c-state
static constexpr size_t SZ_VAC  = (size_t)2 * 256 * 256 * 4;     // f32 vacc-state
static constexpr size_t SZ_VOUT = (size_t)2 * 128 * 512 * 4;     // f32 [2][128][512]
static constexpr size_t SZ_EMB  = (size_t)VOCAB * EPAD * 2;      // bf16 emb table padded (32 MB)
static constexpr size_t SZ_PAD  = (size_t)512 * 1024;            // shared overrun pad after slab1
static constexpr size_t FIXED_B = SZ_WIH + SZ_WPK + SZ_SW + SZ_BIAS + SZ_HSV + SZ_CST + SZ_VAC + SZ_VOUT + SZ_EMB + SZ_PAD;
static constexpr size_t SZ_STEP = (size_t)2 * 256 * 1024 * 2;    // ginc bytes per timestep (1 MB, both dirs)

// pack permutation: pack p = w*128 + q*16 + ul  (w=wave 0..7, q=uh*4+gate, ul 0..15)
//   -> logical Whh/Wih row jlog = (q&3)*256 + w*32 + (q>>2)*16 + ul
// sigma (ginc column) s = w*128 + uh*64 + ul*4 + gate  (gates contiguous per cell)

__device__ __forceinline__ float bf2f(u16 u) {
  union { float f; unsigned int i; } v; v.i = ((unsigned int)u) << 16; return v.f;
}
__device__ __forceinline__ u16 f2bf(float f) {
  union { float f; unsigned int i; } v; v.f = f;
  unsigned int r = v.i + 0x7fffu + ((v.i >> 16) & 1u);   // RNE (finite inputs)
  return (u16)(r >> 16);
}
__device__ __forceinline__ void gload_lds16(const void* g, void* l) {
  __builtin_amdgcn_global_load_lds((const __attribute__((address_space(1))) void*)g,
                                   (__attribute__((address_space(3))) void*)l, 16, 0, 0);
}
// order LDS ops across waves WITHOUT draining vmcnt
__device__ __forceinline__ void lds_barrier() {
  asm volatile("s_waitcnt lgkmcnt(0)" ::: "memory");
  __builtin_amdgcn_s_barrier();
}
// intra-wave LDS exchange fence (R13 bug fix): pins write->read order vs compiler AA
__device__ __forceinline__ void wave_lds_fence() {
  asm volatile("s_waitcnt lgkmcnt(0)" ::: "memory");
  __builtin_amdgcn_sched_barrier(0);
}
// counted-vmcnt tile sync (T4): own loads for the tile-to-read retired (2 newer stay
// in flight), then barrier so ALL waves' loads for it are retired. Never vmcnt(0).
__device__ __forceinline__ void tile_barrier_vm2() {
  asm volatile("s_waitcnt vmcnt(2)" ::: "memory");
  __builtin_amdgcn_s_barrier();
}

// ---------------- prep: Wih->bf16 padded (pack-row order), bias sum (pack order) ----------------
__global__ void prep_kernel(const float* wih_f, const float* bih_f, const float* bhh_f,
                            const float* wih_b, const float* bih_b, const float* bhh_b,
                            u16* wih_bf, float* bias)
{
  int tid = blockIdx.x * blockDim.x + threadIdx.x;
  if (tid < 2 * 1024 * EPAD) {
    int d = tid / (1024 * EPAD); int rr = tid % (1024 * EPAD);
    int p = rr / EPAD; int k = rr % EPAD;
    int w = p >> 7, q = (p >> 4) & 7, ul = p & 15;
    int jlog = (q & 3) * 256 + w * 32 + (q >> 2) * 16 + ul;
    const float* wsrc = d ? wih_b : wih_f;
    wih_bf[tid] = (k < EDIM) ? f2bf(wsrc[(size_t)jlog * EDIM + k]) : (u16)0;
  }
  int t2 = tid - 2 * 1024 * EPAD;
  if (t2 >= 0 && t2 < 2 * 1024) {
    int d = t2 >> 10; int p = t2 & 1023;
    int w = p >> 7, q = (p >> 4) & 7, ul = p & 15;
    int jlog = (q & 3) * 256 + w * 32 + (q >> 2) * 16 + ul;
    bias[t2] = d ? (bih_b[jlog] + bhh_b[jlog]) : (bih_f[jlog] + bhh_f[jlog]);
  }
}

// ---------------- emb -> bf16, K padded 300->320 (one-time) ----------------
__global__ void embconv_kernel(const float* emb, u16* embbf)
{
  int r = blockIdx.x;
  int k = threadIdx.x;     // 320
  embbf[(size_t)r * EPAD + k] = (k < EDIM) ? f2bf(emb[(size_t)r * EDIM + k]) : (u16)0;
}

// ---------------- Whh -> i8 quant + MFMA-fragment pack (8-wave pack order) ----------------
__global__ void whhq_kernel(const float* whh_f, const float* whh_b, char* wpk, float* sw)
{
  int jp = blockIdx.x;             // 0..2047 = d*1024 + pack p
  int t = threadIdx.x;             // 64
  int d = jp >> 10, p = jp & 1023;
  int w = p >> 7, q = (p >> 4) & 7, ul = p & 15;
  int jlog = (q & 3) * 256 + w * 32 + (q >> 2) * 16 + ul;
  const float* src = (d ? whh_b : whh_f) + (size_t)jlog * 256;
  float v[4]; float m = 0.f;
  #pragma unroll
  for (int kk = 0; kk < 4; ++kk) { v[kk] = src[t * 4 + kk]; m = fmaxf(m, fabsf(v[kk])); }
  #pragma unroll
  for (int off = 32; off > 0; off >>= 1) m = fmaxf(m, __shfl_xor(m, off));
  float sunit = m / 127.f;
  if (sunit < 1e-30f) sunit = 1e-30f;
  unsigned int pk = 0;
  #pragma unroll
  for (int kk = 0; kk < 4; ++kk) {
    int qv = (int)rintf(v[kk] / sunit);
    qv = qv > 127 ? 127 : (qv < -127 ? -127 : qv);
    pk |= ((unsigned int)(qv & 255)) << (8 * kk);
  }
  size_t base = ((((size_t)(d * 8 + w) * 8 + q) * 4 + (t >> 4)) * 64
                 + (((t >> 2) & 3) * 16 + ul)) * 16 + (t & 3) * 4;
  *(unsigned int*)&wpk[base] = pk;
  if (t == 0) sw[jp] = sunit / 127.f;
}

// ---------------- gemm body: fused gather + input projection, A in REGISTERS ----------------
// Block = 128 M-rows x full N=1024, 8 waves; wave = 16 rows x all cols.
// A: 10 s16x8 frags/lane (40 VGPR). B: 3x16KB buffers, loads issued 2 tiles ahead,
// counted vmcnt(2)+s_barrier per tile (never vmcnt(0) -> fetch latency stays hidden).
__device__ __forceinline__ void gemm_body(
    int bid, const int* __restrict__ x1, const int* __restrict__ x2,
    const u16* __restrict__ embbf, const u16* __restrict__ wih_bf,
    const float* __restrict__ bias, u16* __restrict__ slab,
    int t0, int T, int logT, char* smem)
{
  u16* Bs = (u16*)smem;                       // 3 x 16 KB
  int d  = bid >> (1 + logT);
  int tl = (bid >> 1) & (T - 1);
  int R0 = (bid & 1) * 128;
  int lane = threadIdx.x & 63;
  int w = threadIdx.x >> 6;                   // 8 waves; wave rows = w*16..+16

  const int* x = (R0 >> 7) ? x2 : x1;
  int t = t0 + tl;
  int tpos = d ? (255 - t) : t;

  // A -> registers
  int rowR = R0 + w * 16 + (lane & 15);
  int tok = x[(rowR & 127) * 256 + tpos];
  const char* arow = (const char*)embbf + (size_t)tok * 640 + (lane >> 4) * 16;
  s16x8 areg[10];
  #pragma unroll
  for (int kc = 0; kc < 10; ++kc)
    areg[kc] = *(const s16x8*)(arow + kc * 64);

  const char* Bbase = (const char*)(wih_bf + (size_t)d * 1024 * EPAD);
  int ar  = lane >> 3;
  int acb = (lane & 7) * 16;
  int swz = ar << 4;

  // issue loads for global tile g (g = nt*5+kt) into buffer g%3
  #define ISSUE_TILE(nnt, nkt, b3)                                                     \
    { _Pragma("unroll")                                                                \
      for (int i = 0; i < 2; ++i) {                                                    \
        int lrow = (i * 8 + w) * 8 + ar;                                               \
        gload_lds16(Bbase + (size_t)((nnt) * 128 + lrow) * 640 + (nkt) * 128 + (acb ^ swz), \
                    (char*)Bs + (b3) * 16384 + (i * 8 + w) * 1024);                    \
      } }

  // prologue: tiles g=0,1 in flight
  ISSUE_TILE(0, 0, 0);
  ISSUE_TILE(0, 1, 1);

  size_t rowbase = (size_t)(d * T + tl) * 256 + R0;
  int ul = lane & 15;

  #pragma unroll
  for (int nt = 0; nt < 8; ++nt) {
    f32x4v acc[8] = {};
    #pragma unroll
    for (int kt = 0; kt < 5; ++kt) {
      const int g = nt * 5 + kt;
      // tile-g loads retired everywhere (g+1's stay in flight), no vmcnt(0)
      tile_barrier_vm2();
      // issue tile g+2 into buffer (g+2)%3 — disjoint from read buf g%3 and g+1's
      {
        const int g2 = g + 2;
        if (g2 < 40) ISSUE_TILE(g2 / 5, g2 % 5, g2 % 3);
      }
      // compute tile g from buffer g%3
      const int b3 = g % 3;
      #pragma unroll
      for (int kc2 = 0; kc2 < 2; ++kc2) {
        int cb = kc2 * 64 + (lane >> 4) * 16;
        #pragma unroll
        for (int nf = 0; nf < 8; ++nf) {
          int rr = nf * 16 + (lane & 15);
          s16x8 b = *(const s16x8*)((const char*)Bs + b3 * 16384 + rr * 128 + (cb ^ ((rr & 7) << 4)));
          acc[nf] = __builtin_amdgcn_mfma_f32_16x16x32_bf16(areg[kt * 2 + kc2], b, acc[nf], 0, 0, 0);
        }
      }
    }
    // epilogue nt: bias + sigma store (u16x4 = 4 gates of one cell); nf = uh*4+gate
    float bv[8];
    #pragma unroll
    for (int nf = 0; nf < 8; ++nf)
      bv[nf] = bias[d * 1024 + nt * 128 + nf * 16 + ul];
    #pragma unroll
    for (int uh = 0; uh < 2; ++uh)
      #pragma unroll
      for (int i = 0; i < 4; ++i) {
        int row = w * 16 + (lane >> 4) * 4 + i;
        u16x4 v;
        #pragma unroll
        for (int g2 = 0; g2 < 4; ++g2)
          v[g2] = f2bf(acc[uh * 4 + g2][i] + bv[uh * 4 + g2]);
        *(u16x4*)(slab + (rowbase + row) * 1024 + nt * 128 + uh * 64 + ul * 4) = v;
      }
  }
  #undef ISSUE_TILE
}

// ---------------- lstm body: R14 structure (all-lane gates, fenced exchange) ----------------
__device__ __forceinline__ void lstm_body(
    int bid, const u16* __restrict__ slab, const i32x4* __restrict__ wpk,
    const float* __restrict__ sw, char* hsave,
    float* cstate, float* vaccst, float* vout,
    const int* __restrict__ len1, const int* __restrict__ len2,
    int t0, int T, char* smem)
{
  char* h = smem;                              // [2 par][2 row][288]
  int* gst = (int*)(smem + 1152);              // [8 wave][64 cell][4 gate]

  const int d = bid >> 7, bt = bid & 127;
  const int tid = threadIdx.x;
  const int lane = tid & 63, w = tid >> 6;
  const int cl = lane & 15;
  const int cr  = lane >> 5;
  const int cuh = (lane >> 4) & 1;
  const int cu  = w * 32 + cuh * 16 + cl;

  i32x4 bfr[8][4];
  #pragma unroll
  for (int q = 0; q < 8; ++q)
    #pragma unroll
    for (int kc = 0; kc < 4; ++kc)
      bfr[q][kc] = wpk[(((size_t)(d * 8 + w) * 8 + q) * 4 + kc) * 64 + lane];
  float swl4[4];
  #pragma unroll
  for (int g = 0; g < 4; ++g)
    swl4[g] = sw[d * 1024 + w * 128 + (cuh * 4 + g) * 16 + cl];

  const int R0 = bt * 2;
  {
    int r = tid >> 8, u = tid & 255;
    h[r * 288 + u] = (t0 > 0) ? hsave[((size_t)d * 256 + R0 + r) * 256 + u] : (char)0;
  }

  const int RR = R0 + cr;
  const int lm = ((RR >> 7) ? len2 : len1)[RR & 127] - 1;
  const size_t sidx = ((size_t)d * 256 + RR) * 256 + cu;
  float c = 0.f, va = 0.f;
  if (t0 > 0) { c = cstate[sidx]; va = vaccst[sidx]; }

  const size_t GSTEP = (size_t)256 * 1024;
  const u16* gcell = slab + ((size_t)d * T * 256 + RR) * 1024 + w * 128 + cuh * 64 + cl * 4;
  u16x4 gv = *(const u16x4*)gcell;
  __syncthreads();

  const bool final_chunk = (t0 + T == 256);
  int par = 0;

  for (int tl = 0; tl < T; ++tl) {
    u16x4 gvn = *(const u16x4*)(gcell + GSTEP * (size_t)(tl + 1));

    // A-frags: mask is (cl<2) only — rows live in lanes {0,1,16,17,32,33,48,49}
    i32x4 a[4] = {{0,0,0,0},{0,0,0,0},{0,0,0,0},{0,0,0,0}};
    if (cl < 2) {
      #pragma unroll
      for (int kc = 0; kc < 4; ++kc)
        a[kc] = *(const i32x4*)&h[(par * 2 + cl) * 288 + kc * 64 + (lane >> 4) * 16];
    }
    i32x4 acc[8];
    #pragma unroll
    for (int q = 0; q < 8; ++q) {
      i32x4 z = {0, 0, 0, 0};
      #pragma unroll
      for (int kc = 0; kc < 4; ++kc)
        z = __builtin_amdgcn_mfma_i32_16x16x64_i8(a[kc], bfr[q][kc], z, 0, 0, 0);
      acc[q] = z;
    }

    if (lane < 16) {
      #pragma unroll
      for (int r2 = 0; r2 < 2; ++r2)
        #pragma unroll
        for (int uh2 = 0; uh2 < 2; ++uh2) {
          i32x4 v = { acc[uh2 * 4 + 0][r2], acc[uh2 * 4 + 1][r2],
                      acc[uh2 * 4 + 2][r2], acc[uh2 * 4 + 3][r2] };
          *(i32x4*)&gst[(w * 64 + r2 * 32 + uh2 * 16 + lane) * 4] = v;
        }
    }
    wave_lds_fence();   // required: compiler may hoist cross-lane read (R13 bug)
    i32x4 g4 = *(const i32x4*)&gst[(w * 64 + lane) * 4];

    {
      float s0 = (float)g4[0] * swl4[0] + bf2f(gv[0]);
      float s1 = (float)g4[1] * swl4[1] + bf2f(gv[1]);
      float s2 = (float)g4[2] * swl4[2] + bf2f(gv[2]);
      float s3 = (float)g4[3] * swl4[3] + bf2f(gv[3]);
      float I = __builtin_amdgcn_rcpf(1.f + __expf(-s0));
      float F = __builtin_amdgcn_rcpf(1.f + __expf(-s1));
      float G = 1.f - 2.f * __builtin_amdgcn_rcpf(__expf(2.f * s2) + 1.f);
      float O = __builtin_amdgcn_rcpf(1.f + __expf(-s3));
      float cn = F * c + I * G;
      c = cn;
      float hn = O * (1.f - 2.f * __builtin_amdgcn_rcpf(__expf(2.f * cn) + 1.f));
      int tmap = d ? (255 - (t0 + tl)) : (t0 + tl);
      if (tmap < lm) va += hn;
      h[((par ^ 1) * 2 + cr) * 288 + cu] = (char)(int)rintf(hn * 127.f);
    }
    lds_barrier();
    gv = gvn;
    par ^= 1;
  }

  cstate[sidx] = c;
  vaccst[sidx] = va;
  if (final_chunk) {
    vout[((size_t)(RR >> 7) * 128 + (RR & 127)) * 512 + d * 256 + cu] = va / (float)lm;
  } else {
    int r = tid >> 8, u = tid & 255;
    hsave[((size_t)d * 256 + R0 + r) * 256 + u] = h[(par * 2 + r) * 288 + u];
  }
}

// ---------------- fused kernel: blocks [0,nL) = lstm(chunk k), rest = gemm(chunk k+1) ----------------
// Zero inter-group dependency (gemm writes the OTHER ginc slab) -> pure co-scheduling.
// __launch_bounds__(512, 2): 2 blocks/CU -> 128 VGPR cap; both bodies fit (R16: (512,4)
// produced a 64-VGPR cap -> catastrophic spills). smem 48KB -> 96KB/CU at 2 blocks.
__global__ void __launch_bounds__(512, 2)
fused_kernel(const int* x1, const int* x2, const u16* embbf, const u16* wih_bf,
             const float* bias, const i32x4* wpk, const float* sw,
             char* hsave, float* cstate, float* vaccst, float* vout,
             const int* len1, const int* len2,
             const u16* lstm_slab, u16* gemm_slab,
             int lstm_t0, int gemm_t0, int nL, int T, int logT)
{
  __shared__ __align__(16) char smem[49152];
  if ((int)blockIdx.x < nL) {
    lstm_body(blockIdx.x, lstm_slab, wpk, sw, hsave, cstate, vaccst, vout,
              len1, len2, lstm_t0, T, smem);
  } else if (gemm_t0 >= 0) {
    gemm_body(blockIdx.x - nL, x1, x2, embbf, wih_bf, bias, gemm_slab,
              gemm_t0, T, logT, smem);
  }
}

// ---------------- MLP head ----------------
__global__ void mlp_kernel(const float* v, const float* W1, const float* b1,
                           const float* W2, const float* b2, const float* Wo, const float* bo,
                           float* out)
{
  __shared__ float vec[512];
  __shared__ float a1[512];
  __shared__ float red[4];
  int b = blockIdx.x;
  int tid = threadIdx.x;   // 256
  for (int i = tid; i < 512; i += 256)
    vec[i] = fabsf(v[(size_t)b * 512 + i] - v[(size_t)(128 + b) * 512 + i]);
  __syncthreads();
  for (int j = tid; j < 512; j += 256) {
    float s = b1[j];
    const float* wr = W1 + (size_t)j * 512;
    for (int k = 0; k < 512; ++k) s += vec[k] * wr[k];
    a1[j] = fmaxf(s, 0.f);
  }
  __syncthreads();
  float s = b2[tid];
  {
    const float* wr = W2 + (size_t)tid * 512;
    for (int k = 0; k < 512; ++k) s += a1[k] * wr[k];
  }
  float p = fmaxf(s, 0.f) * Wo[tid];
  for (int off = 32; off > 0; off >>= 1) p += __shfl_down(p, off);
  if ((tid & 63) == 0) red[tid >> 6] = p;
  __syncthreads();
  if (tid == 0) {
    float logit = red[0] + red[1] + red[2] + red[3] + bo[0];
    out[b] = logit;
    out[128 + b] = 1.f / (1.f + __expf(-logit));
  }
}

extern "C" void kernel_launch(void* const* d_in, const int* in_sizes, int n_in,
                              void* d_out, int out_size, void* d_ws, size_t ws_size,
                              hipStream_t stream)
{
  const int*   x1    = (const int*)d_in[0];
  const int*   x2    = (const int*)d_in[1];
  const int*   len1  = (const int*)d_in[2];
  const int*   len2  = (const int*)d_in[3];
  const float* emb   = (const float*)d_in[4];
  const float* wih_f = (const float*)d_in[5];
  const float* whh_f = (const float*)d_in[6];
  const float* bih_f = (const float*)d_in[7];
  const float* bhh_f = (const float*)d_in[8];
  const float* wih_b = (const float*)d_in[9];
  const float* whh_b = (const float*)d_in[10];
  const float* bih_b = (const float*)d_in[11];
  const float* bhh_b = (const float*)d_in[12];
  const float* W1    = (const float*)d_in[13];
  const float* b1    = (const float*)d_in[14];
  const float* W2    = (const float*)d_in[15];
  const float* b2    = (const float*)d_in[16];
  const float* Wo    = (const float*)d_in[17];
  const float* bo    = (const float*)d_in[18];

  char* p = (char*)d_ws;
  u16*   wih_bf = (u16*)p;          p += SZ_WIH;
  char*  wpk    = (char*)p;         p += SZ_WPK;
  float* swp    = (float*)p;        p += SZ_SW;
  float* bias   = (float*)p;        p += SZ_BIAS;
  char*  hsave  = (char*)p;         p += SZ_HSV;
  float* cst    = (float*)p;        p += SZ_CST;
  float* vac    = (float*)p;        p += SZ_VAC;
  float* vout   = (float*)p;        p += SZ_VOUT;
  u16*   embbf  = (u16*)p;          p += SZ_EMB;

  // chunk T: start at 128 (guarantees >=1 fused middle); shrink if workspace demands
  int T = 128;
  while (T > 1 && FIXED_B + (size_t)2 * T * SZ_STEP > ws_size) T >>= 1;
  int logT = __builtin_ctz((unsigned)T);
  u16* slab0 = (u16*)p;             p += (size_t)T * SZ_STEP;
  u16* slab1 = (u16*)p;
  u16* slabs[2] = { slab0, slab1 };

  {
    int total = 2 * 1024 * EPAD + 2 * 1024;
    prep_kernel<<<(total + 255) / 256, 256, 0, stream>>>(
        wih_f, bih_f, bhh_f, wih_b, bih_b, bhh_b, wih_bf, bias);
  }
  whhq_kernel<<<2048, 64, 0, stream>>>(whh_f, whh_b, wpk, swp);
  embconv_kernel<<<VOCAB, EPAD, 0, stream>>>(emb, embbf);

  int NCH = 256 / T;
  // pipeline: gemm(0); { lstm(ch-1) || gemm(ch) }; lstm(NCH-1)
  fused_kernel<<<4 * T, 512, 0, stream>>>(x1, x2, embbf, wih_bf, bias,
                                          (const i32x4*)wpk, swp, hsave, cst, vac, vout,
                                          len1, len2, slabs[0], slabs[0],
                                          -1, 0, 0, T, logT);
  for (int ch = 1; ch < NCH; ++ch) {
    fused_kernel<<<256 + 4 * T, 512, 0, stream>>>(x1, x2, embbf, wih_bf, bias,
                                                  (const i32x4*)wpk, swp, hsave, cst, vac, vout,
                                                  len1, len2, slabs[(ch - 1) & 1], slabs[ch & 1],
                                                  (ch - 1) * T, ch * T, 256, T, logT);
  }
  fused_kernel<<<256, 512, 0, stream>>>(x1, x2, embbf, wih_bf, bias,
                                        (const i32x4*)wpk, swp, hsave, cst, vac, vout,
                                        len1, len2, slabs[(NCH - 1) & 1], slabs[0],
                                        (NCH - 1) * T, -1, 256, T, logT);

  mlp_kernel<<<128, 256, 0, stream>>>(vout, W1, b1, W2, b2, Wo, bo, (float*)d_out);
}

// Round 20
// 423.515 us; speedup vs baseline: 1.0587x; 1.0458x over previous
//
#include <hip/hip_runtime.h>
#include <hip/hip_bf16.h>
#include <math.h>

typedef unsigned short u16;
typedef short s16x8 __attribute__((ext_vector_type(8)));
typedef float f32x4v __attribute__((ext_vector_type(4)));
typedef int i32x4 __attribute__((ext_vector_type(4)));
typedef unsigned short u16x4 __attribute__((ext_vector_type(4)));

#define EDIM 300
#define EPAD 320
#define VOCAB 50000

// ---- fixed workspace layout (bytes) ----
static constexpr size_t SZ_WIH  = (size_t)2 * 1024 * EPAD * 2;   // bf16 [2][1024 pack][320]
static constexpr size_t SZ_WPK  = (size_t)2 * 1024 * 256;        // i8 packed Whh frags
static constexpr size_t SZ_SW   = (size_t)2 * 1024 * 4;          // f32 per-row scale (pack order)
static constexpr size_t SZ_BIAS = (size_t)2 * 1024 * 4;          // f32 (pack order)
static constexpr size_t SZ_HSV  = (size_t)2 * 256 * 256;         // i8 h chunk-boundary save
static constexpr size_t SZ_CST  = (size_t)2 * 256 * 256 * 4;     // f32 c-state
static constexpr size_t SZ_VAC  = (size_t)2 * 256 * 256 * 4;     // f32 vacc-state
static constexpr size_t SZ_VOUT = (size_t)2 * 128 * 512 * 4;     // f32 [2][128][512]
static constexpr size_t SZ_EMB  = (size_t)VOCAB * EPAD * 2;      // bf16 emb table padded (32 MB)
static constexpr size_t SZ_PAD  = (size_t)512 * 1024;            // shared overrun pad after slab1
static constexpr size_t FIXED_B = SZ_WIH + SZ_WPK + SZ_SW + SZ_BIAS + SZ_HSV + SZ_CST + SZ_VAC + SZ_VOUT + SZ_EMB + SZ_PAD;
static constexpr size_t SZ_STEP = (size_t)2 * 256 * 1024 * 2;    // ginc bytes per timestep (1 MB, both dirs)

// pack permutation: pack p = w*128 + q*16 + ul  (w=wave 0..7, q=uh*4+gate, ul 0..15)
//   -> logical Whh/Wih row jlog = (q&3)*256 + w*32 + (q>>2)*16 + ul
// sigma (ginc column) s = w*128 + uh*64 + ul*4 + gate  (gates contiguous per cell)

__device__ __forceinline__ float bf2f(u16 u) {
  union { float f; unsigned int i; } v; v.i = ((unsigned int)u) << 16; return v.f;
}
__device__ __forceinline__ u16 f2bf(float f) {
  union { float f; unsigned int i; } v; v.f = f;
  unsigned int r = v.i + 0x7fffu + ((v.i >> 16) & 1u);   // RNE (finite inputs)
  return (u16)(r >> 16);
}
__device__ __forceinline__ void gload_lds16(const void* g, void* l) {
  __builtin_amdgcn_global_load_lds((const __attribute__((address_space(1))) void*)g,
                                   (__attribute__((address_space(3))) void*)l, 16, 0, 0);
}
// order LDS ops across waves WITHOUT draining vmcnt
__device__ __forceinline__ void lds_barrier() {
  asm volatile("s_waitcnt lgkmcnt(0)" ::: "memory");
  __builtin_amdgcn_s_barrier();
}
// intra-wave LDS exchange fence (R13 bug fix): pins write->read order vs compiler AA
__device__ __forceinline__ void wave_lds_fence() {
  asm volatile("s_waitcnt lgkmcnt(0)" ::: "memory");
  __builtin_amdgcn_sched_barrier(0);
}
// counted-vmcnt tile sync (T4): own loads for the tile-to-read retired (2 newer stay
// in flight), then barrier so ALL waves' loads for it are retired. Never vmcnt(0).
__device__ __forceinline__ void tile_barrier_vm2() {
  asm volatile("s_waitcnt vmcnt(2)" ::: "memory");
  __builtin_amdgcn_s_barrier();
}

// ---------------- merged setup: embconv + Wih pack + bias + Whh quant, ONE launch ----------------
// Replaces 3 small-block launches (~130 us of latency-bound dispatches) with one
// vectorized kernel (~100 MB traffic).
__global__ void __launch_bounds__(256)
setup_kernel(const float* __restrict__ emb,
             const float* __restrict__ wih_f, const float* __restrict__ wih_b,
             const float* __restrict__ whh_f, const float* __restrict__ whh_b,
             const float* __restrict__ bih_f, const float* __restrict__ bhh_f,
             const float* __restrict__ bih_b, const float* __restrict__ bhh_b,
             u16* __restrict__ embbf, u16* __restrict__ wih_bf,
             float* __restrict__ bias, char* __restrict__ wpk, float* __restrict__ sw)
{
  const int EMB_BLKS  = (VOCAB * 80 + 255) / 256;     // 15625 (u16x4 chunks)
  const int WIH_BLKS  = (2 * 1024 * 80 + 255) / 256;  // 640
  const int BIAS_BLKS = 8;
  int b = blockIdx.x;
  int tid = threadIdx.x;

  if (b < EMB_BLKS) {                      // §A: emb -> bf16 padded
    int c = b * 256 + tid;
    if (c < VOCAB * 80) {
      int r = c / 80, k4 = (c % 80) * 4;
      u16x4 v = {0, 0, 0, 0};
      if (k4 < EDIM) {
        f32x4v f = *(const f32x4v*)(emb + (size_t)r * EDIM + k4);
        v[0] = f2bf(f[0]); v[1] = f2bf(f[1]); v[2] = f2bf(f[2]); v[3] = f2bf(f[3]);
      }
      *(u16x4*)(embbf + (size_t)r * EPAD + k4) = v;
    }
    return;
  }
  b -= EMB_BLKS;
  if (b < WIH_BLKS) {                      // §B: Wih -> bf16 padded, pack-row order
    int c = b * 256 + tid;
    if (c < 2 * 1024 * 80) {
      int dp = c / 80, k4 = (c % 80) * 4;
      int d = dp >> 10, p = dp & 1023;
      int w = p >> 7, q = (p >> 4) & 7, ul = p & 15;
      int jlog = (q & 3) * 256 + w * 32 + (q >> 2) * 16 + ul;
      u16x4 v = {0, 0, 0, 0};
      if (k4 < EDIM) {
        f32x4v f = *(const f32x4v*)((d ? wih_b : wih_f) + (size_t)jlog * EDIM + k4);
        v[0] = f2bf(f[0]); v[1] = f2bf(f[1]); v[2] = f2bf(f[2]); v[3] = f2bf(f[3]);
      }
      *(u16x4*)(wih_bf + (size_t)dp * EPAD + k4) = v;
    }
    return;
  }
  b -= WIH_BLKS;
  if (b < BIAS_BLKS) {                     // §C: bias = bih + bhh (pack order)
    int t2 = b * 256 + tid;
    if (t2 < 2 * 1024) {
      int d = t2 >> 10; int p = t2 & 1023;
      int w = p >> 7, q = (p >> 4) & 7, ul = p & 15;
      int jlog = (q & 3) * 256 + w * 32 + (q >> 2) * 16 + ul;
      bias[t2] = d ? (bih_b[jlog] + bhh_b[jlog]) : (bih_f[jlog] + bhh_f[jlog]);
    }
    return;
  }
  b -= BIAS_BLKS;
  {                                        // §D: Whh -> i8 quant + frag pack (4 x 64-lane groups)
    int jp = b * 4 + (tid >> 6);           // 0..2047 = d*1024 + pack p
    if (jp >= 2048) return;
    int t = tid & 63;
    int d = jp >> 10, p = jp & 1023;
    int w = p >> 7, q = (p >> 4) & 7, ul = p & 15;
    int jlog = (q & 3) * 256 + w * 32 + (q >> 2) * 16 + ul;
    const float* src = (d ? whh_b : whh_f) + (size_t)jlog * 256;
    float v[4]; float m = 0.f;
    #pragma unroll
    for (int kk = 0; kk < 4; ++kk) { v[kk] = src[t * 4 + kk]; m = fmaxf(m, fabsf(v[kk])); }
    #pragma unroll
    for (int off = 32; off > 0; off >>= 1) m = fmaxf(m, __shfl_xor(m, off));
    float sunit = m / 127.f;
    if (sunit < 1e-30f) sunit = 1e-30f;
    unsigned int pk = 0;
    #pragma unroll
    for (int kk = 0; kk < 4; ++kk) {
      int qv = (int)rintf(v[kk] / sunit);
      qv = qv > 127 ? 127 : (qv < -127 ? -127 : qv);
      pk |= ((unsigned int)(qv & 255)) << (8 * kk);
    }
    size_t base = ((((size_t)(d * 8 + w) * 8 + q) * 4 + (t >> 4)) * 64
                   + (((t >> 2) & 3) * 16 + ul)) * 16 + (t & 3) * 4;
    *(unsigned int*)&wpk[base] = pk;
    if (t == 0) sw[jp] = sunit / 127.f;
  }
}

// ---------------- gemm body: fused gather + input projection, A in REGISTERS ----------------
// Block = 128 M-rows x full N=1024, 8 waves; wave = 16 rows x all cols.
// A: 10 s16x8 frags/lane (40 VGPR). B: 3x16KB buffers, loads issued 2 tiles ahead,
// counted vmcnt(2)+s_barrier per tile (never vmcnt(0) -> fetch latency stays hidden).
__device__ __forceinline__ void gemm_body(
    int bid, const int* __restrict__ x1, const int* __restrict__ x2,
    const u16* __restrict__ embbf, const u16* __restrict__ wih_bf,
    const float* __restrict__ bias, u16* __restrict__ slab,
    int t0, int T, int logT, char* smem)
{
  u16* Bs = (u16*)smem;                       // 3 x 16 KB
  int d  = bid >> (1 + logT);
  int tl = (bid >> 1) & (T - 1);
  int R0 = (bid & 1) * 128;
  int lane = threadIdx.x & 63;
  int w = threadIdx.x >> 6;                   // 8 waves; wave rows = w*16..+16

  const int* x = (R0 >> 7) ? x2 : x1;
  int t = t0 + tl;
  int tpos = d ? (255 - t) : t;

  // A -> registers
  int rowR = R0 + w * 16 + (lane & 15);
  int tok = x[(rowR & 127) * 256 + tpos];
  const char* arow = (const char*)embbf + (size_t)tok * 640 + (lane >> 4) * 16;
  s16x8 areg[10];
  #pragma unroll
  for (int kc = 0; kc < 10; ++kc)
    areg[kc] = *(const s16x8*)(arow + kc * 64);

  const char* Bbase = (const char*)(wih_bf + (size_t)d * 1024 * EPAD);
  int ar  = lane >> 3;
  int acb = (lane & 7) * 16;
  int swz = ar << 4;

  // issue loads for global tile g (g = nt*5+kt) into buffer g%3
  #define ISSUE_TILE(nnt, nkt, b3)                                                     \
    { _Pragma("unroll")                                                                \
      for (int i = 0; i < 2; ++i) {                                                    \
        int lrow = (i * 8 + w) * 8 + ar;                                               \
        gload_lds16(Bbase + (size_t)((nnt) * 128 + lrow) * 640 + (nkt) * 128 + (acb ^ swz), \
                    (char*)Bs + (b3) * 16384 + (i * 8 + w) * 1024);                    \
      } }

  // prologue: tiles g=0,1 in flight
  ISSUE_TILE(0, 0, 0);
  ISSUE_TILE(0, 1, 1);

  size_t rowbase = (size_t)(d * T + tl) * 256 + R0;
  int ul = lane & 15;

  #pragma unroll
  for (int nt = 0; nt < 8; ++nt) {
    f32x4v acc[8] = {};
    #pragma unroll
    for (int kt = 0; kt < 5; ++kt) {
      const int g = nt * 5 + kt;
      // tile-g loads retired everywhere (g+1's stay in flight), no vmcnt(0)
      tile_barrier_vm2();
      // issue tile g+2 into buffer (g+2)%3 — disjoint from read buf g%3 and g+1's
      {
        const int g2 = g + 2;
        if (g2 < 40) ISSUE_TILE(g2 / 5, g2 % 5, g2 % 3);
      }
      // compute tile g from buffer g%3
      const int b3 = g % 3;
      #pragma unroll
      for (int kc2 = 0; kc2 < 2; ++kc2) {
        int cb = kc2 * 64 + (lane >> 4) * 16;
        #pragma unroll
        for (int nf = 0; nf < 8; ++nf) {
          int rr = nf * 16 + (lane & 15);
          s16x8 b = *(const s16x8*)((const char*)Bs + b3 * 16384 + rr * 128 + (cb ^ ((rr & 7) << 4)));
          acc[nf] = __builtin_amdgcn_mfma_f32_16x16x32_bf16(areg[kt * 2 + kc2], b, acc[nf], 0, 0, 0);
        }
      }
    }
    // epilogue nt: bias + sigma store (u16x4 = 4 gates of one cell); nf = uh*4+gate
    float bv[8];
    #pragma unroll
    for (int nf = 0; nf < 8; ++nf)
      bv[nf] = bias[d * 1024 + nt * 128 + nf * 16 + ul];
    #pragma unroll
    for (int uh = 0; uh < 2; ++uh)
      #pragma unroll
      for (int i = 0; i < 4; ++i) {
        int row = w * 16 + (lane >> 4) * 4 + i;
        u16x4 v;
        #pragma unroll
        for (int g2 = 0; g2 < 4; ++g2)
          v[g2] = f2bf(acc[uh * 4 + g2][i] + bv[uh * 4 + g2]);
        *(u16x4*)(slab + (rowbase + row) * 1024 + nt * 128 + uh * 64 + ul * 4) = v;
      }
  }
  #undef ISSUE_TILE
}

// ---------------- lstm body: R14 structure (all-lane gates, fenced exchange) ----------------
__device__ __forceinline__ void lstm_body(
    int bid, const u16* __restrict__ slab, const i32x4* __restrict__ wpk,
    const float* __restrict__ sw, char* hsave,
    float* cstate, float* vaccst, float* vout,
    const int* __restrict__ len1, const int* __restrict__ len2,
    int t0, int T, char* smem)
{
  char* h = smem;                              // [2 par][2 row][288]
  int* gst = (int*)(smem + 1152);              // [8 wave][64 cell][4 gate]

  const int d = bid >> 7, bt = bid & 127;
  const int tid = threadIdx.x;
  const int lane = tid & 63, w = tid >> 6;
  const int cl = lane & 15;
  const int cr  = lane >> 5;
  const int cuh = (lane >> 4) & 1;
  const int cu  = w * 32 + cuh * 16 + cl;

  i32x4 bfr[8][4];
  #pragma unroll
  for (int q = 0; q < 8; ++q)
    #pragma unroll
    for (int kc = 0; kc < 4; ++kc)
      bfr[q][kc] = wpk[(((size_t)(d * 8 + w) * 8 + q) * 4 + kc) * 64 + lane];
  float swl4[4];
  #pragma unroll
  for (int g = 0; g < 4; ++g)
    swl4[g] = sw[d * 1024 + w * 128 + (cuh * 4 + g) * 16 + cl];

  const int R0 = bt * 2;
  {
    int r = tid >> 8, u = tid & 255;
    h[r * 288 + u] = (t0 > 0) ? hsave[((size_t)d * 256 + R0 + r) * 256 + u] : (char)0;
  }

  const int RR = R0 + cr;
  const int lm = ((RR >> 7) ? len2 : len1)[RR & 127] - 1;
  const size_t sidx = ((size_t)d * 256 + RR) * 256 + cu;
  float c = 0.f, va = 0.f;
  if (t0 > 0) { c = cstate[sidx]; va = vaccst[sidx]; }

  const size_t GSTEP = (size_t)256 * 1024;
  const u16* gcell = slab + ((size_t)d * T * 256 + RR) * 1024 + w * 128 + cuh * 64 + cl * 4;
  u16x4 gv = *(const u16x4*)gcell;
  __syncthreads();

  const bool final_chunk = (t0 + T == 256);
  int par = 0;

  for (int tl = 0; tl < T; ++tl) {
    u16x4 gvn = *(const u16x4*)(gcell + GSTEP * (size_t)(tl + 1));

    // A-frags: mask is (cl<2) only — rows live in lanes {0,1,16,17,32,33,48,49}
    i32x4 a[4] = {{0,0,0,0},{0,0,0,0},{0,0,0,0},{0,0,0,0}};
    if (cl < 2) {
      #pragma unroll
      for (int kc = 0; kc < 4; ++kc)
        a[kc] = *(const i32x4*)&h[(par * 2 + cl) * 288 + kc * 64 + (lane >> 4) * 16];
    }
    i32x4 acc[8];
    #pragma unroll
    for (int q = 0; q < 8; ++q) {
      i32x4 z = {0, 0, 0, 0};
      #pragma unroll
      for (int kc = 0; kc < 4; ++kc)
        z = __builtin_amdgcn_mfma_i32_16x16x64_i8(a[kc], bfr[q][kc], z, 0, 0, 0);
      acc[q] = z;
    }

    if (lane < 16) {
      #pragma unroll
      for (int r2 = 0; r2 < 2; ++r2)
        #pragma unroll
        for (int uh2 = 0; uh2 < 2; ++uh2) {
          i32x4 v = { acc[uh2 * 4 + 0][r2], acc[uh2 * 4 + 1][r2],
                      acc[uh2 * 4 + 2][r2], acc[uh2 * 4 + 3][r2] };
          *(i32x4*)&gst[(w * 64 + r2 * 32 + uh2 * 16 + lane) * 4] = v;
        }
    }
    wave_lds_fence();   // required: compiler may hoist cross-lane read (R13 bug)
    i32x4 g4 = *(const i32x4*)&gst[(w * 64 + lane) * 4];

    {
      float s0 = (float)g4[0] * swl4[0] + bf2f(gv[0]);
      float s1 = (float)g4[1] * swl4[1] + bf2f(gv[1]);
      float s2 = (float)g4[2] * swl4[2] + bf2f(gv[2]);
      float s3 = (float)g4[3] * swl4[3] + bf2f(gv[3]);
      float I = __builtin_amdgcn_rcpf(1.f + __expf(-s0));
      float F = __builtin_amdgcn_rcpf(1.f + __expf(-s1));
      float G = 1.f - 2.f * __builtin_amdgcn_rcpf(__expf(2.f * s2) + 1.f);
      float O = __builtin_amdgcn_rcpf(1.f + __expf(-s3));
      float cn = F * c + I * G;
      c = cn;
      float hn = O * (1.f - 2.f * __builtin_amdgcn_rcpf(__expf(2.f * cn) + 1.f));
      int tmap = d ? (255 - (t0 + tl)) : (t0 + tl);
      if (tmap < lm) va += hn;
      h[((par ^ 1) * 2 + cr) * 288 + cu] = (char)(int)rintf(hn * 127.f);
    }
    lds_barrier();
    gv = gvn;
    par ^= 1;
  }

  cstate[sidx] = c;
  vaccst[sidx] = va;
  if (final_chunk) {
    vout[((size_t)(RR >> 7) * 128 + (RR & 127)) * 512 + d * 256 + cu] = va / (float)lm;
  } else {
    int r = tid >> 8, u = tid & 255;
    hsave[((size_t)d * 256 + R0 + r) * 256 + u] = h[(par * 2 + r) * 288 + u];
  }
}

// ---------------- fused kernel: blocks [0,nL) = lstm(chunk k), rest = gemm(chunk k+1) ----------------
// Zero inter-group dependency (gemm writes the OTHER ginc slab) -> pure co-scheduling.
// __launch_bounds__(512, 2): 2 blocks/CU -> 128 VGPR cap; both bodies fit (R16: (512,4)
// produced a 64-VGPR cap -> catastrophic spills). smem 48KB -> 96KB/CU at 2 blocks.
__global__ void __launch_bounds__(512, 2)
fused_kernel(const int* x1, const int* x2, const u16* embbf, const u16* wih_bf,
             const float* bias, const i32x4* wpk, const float* sw,
             char* hsave, float* cstate, float* vaccst, float* vout,
             const int* len1, const int* len2,
             const u16* lstm_slab, u16* gemm_slab,
             int lstm_t0, int gemm_t0, int nL, int T, int logT)
{
  __shared__ __align__(16) char smem[49152];
  if ((int)blockIdx.x < nL) {
    lstm_body(blockIdx.x, lstm_slab, wpk, sw, hsave, cstate, vaccst, vout,
              len1, len2, lstm_t0, T, smem);
  } else if (gemm_t0 >= 0) {
    gemm_body(blockIdx.x - nL, x1, x2, embbf, wih_bf, bias, gemm_slab,
              gemm_t0, T, logT, smem);
  }
}

// ---------------- MLP head ----------------
__global__ void mlp_kernel(const float* v, const float* W1, const float* b1,
                           const float* W2, const float* b2, const float* Wo, const float* bo,
                           float* out)
{
  __shared__ float vec[512];
  __shared__ float a1[512];
  __shared__ float red[4];
  int b = blockIdx.x;
  int tid = threadIdx.x;   // 256
  for (int i = tid; i < 512; i += 256)
    vec[i] = fabsf(v[(size_t)b * 512 + i] - v[(size_t)(128 + b) * 512 + i]);
  __syncthreads();
  for (int j = tid; j < 512; j += 256) {
    float s = b1[j];
    const float* wr = W1 + (size_t)j * 512;
    for (int k = 0; k < 512; ++k) s += vec[k] * wr[k];
    a1[j] = fmaxf(s, 0.f);
  }
  __syncthreads();
  float s = b2[tid];
  {
    const float* wr = W2 + (size_t)tid * 512;
    for (int k = 0; k < 512; ++k) s += a1[k] * wr[k];
  }
  float p = fmaxf(s, 0.f) * Wo[tid];
  for (int off = 32; off > 0; off >>= 1) p += __shfl_down(p, off);
  if ((tid & 63) == 0) red[tid >> 6] = p;
  __syncthreads();
  if (tid == 0) {
    float logit = red[0] + red[1] + red[2] + red[3] + bo[0];
    out[b] = logit;
    out[128 + b] = 1.f / (1.f + __expf(-logit));
  }
}

extern "C" void kernel_launch(void* const* d_in, const int* in_sizes, int n_in,
                              void* d_out, int out_size, void* d_ws, size_t ws_size,
                              hipStream_t stream)
{
  const int*   x1    = (const int*)d_in[0];
  const int*   x2    = (const int*)d_in[1];
  const int*   len1  = (const int*)d_in[2];
  const int*   len2  = (const int*)d_in[3];
  const float* emb   = (const float*)d_in[4];
  const float* wih_f = (const float*)d_in[5];
  const float* whh_f = (const float*)d_in[6];
  const float* bih_f = (const float*)d_in[7];
  const float* bhh_f = (const float*)d_in[8];
  const float* wih_b = (const float*)d_in[9];
  const float* whh_b = (const float*)d_in[10];
  const float* bih_b = (const float*)d_in[11];
  const float* bhh_b = (const float*)d_in[12];
  const float* W1    = (const float*)d_in[13];
  const float* b1    = (const float*)d_in[14];
  const float* W2    = (const float*)d_in[15];
  const float* b2    = (const float*)d_in[16];
  const float* Wo    = (const float*)d_in[17];
  const float* bo    = (const float*)d_in[18];

  char* p = (char*)d_ws;
  u16*   wih_bf = (u16*)p;          p += SZ_WIH;
  char*  wpk    = (char*)p;         p += SZ_WPK;
  float* swp    = (float*)p;        p += SZ_SW;
  float* bias   = (float*)p;        p += SZ_BIAS;
  char*  hsave  = (char*)p;         p += SZ_HSV;
  float* cst    = (float*)p;        p += SZ_CST;
  float* vac    = (float*)p;        p += SZ_VAC;
  float* vout   = (float*)p;        p += SZ_VOUT;
  u16*   embbf  = (u16*)p;          p += SZ_EMB;

  // chunk T: start at 128 (guarantees >=1 fused middle); shrink if workspace demands
  int T = 128;
  while (T > 1 && FIXED_B + (size_t)2 * T * SZ_STEP > ws_size) T >>= 1;
  int logT = __builtin_ctz((unsigned)T);
  u16* slab0 = (u16*)p;             p += (size_t)T * SZ_STEP;
  u16* slab1 = (u16*)p;
  u16* slabs[2] = { slab0, slab1 };

  // merged setup: embconv + Wih pack + bias + Whh quant in one launch
  {
    const int EMB_BLKS  = (VOCAB * 80 + 255) / 256;
    const int WIH_BLKS  = (2 * 1024 * 80 + 255) / 256;
    const int BIAS_BLKS = 8;
    const int WHH_BLKS  = 512;
    int total_blocks = EMB_BLKS + WIH_BLKS + BIAS_BLKS + WHH_BLKS;
    setup_kernel<<<total_blocks, 256, 0, stream>>>(
        emb, wih_f, wih_b, whh_f, whh_b, bih_f, bhh_f, bih_b, bhh_b,
        embbf, wih_bf, bias, wpk, swp);
  }

  int NCH = 256 / T;
  // pipeline: gemm(0); { lstm(ch-1) || gemm(ch) }; lstm(NCH-1)
  fused_kernel<<<4 * T, 512, 0, stream>>>(x1, x2, embbf, wih_bf, bias,
                                          (const i32x4*)wpk, swp, hsave, cst, vac, vout,
                                          len1, len2, slabs[0], slabs[0],
                                          -1, 0, 0, T, logT);
  for (int ch = 1; ch < NCH; ++ch) {
    fused_kernel<<<256 + 4 * T, 512, 0, stream>>>(x1, x2, embbf, wih_bf, bias,
                                                  (const i32x4*)wpk, swp, hsave, cst, vac, vout,
                                                  len1, len2, slabs[(ch - 1) & 1], slabs[ch & 1],
                                                  (ch - 1) * T, ch * T, 256, T, logT);
  }
  fused_kernel<<<256, 512, 0, stream>>>(x1, x2, embbf, wih_bf, bias,
                                        (const i32x4*)wpk, swp, hsave, cst, vac, vout,
                                        len1, len2, slabs[(NCH - 1) & 1], slabs[0],
                                        (NCH - 1) * T, -1, 256, T, logT);

  mlp_kernel<<<128, 256, 0, stream>>>(vout, W1, b1, W2, b2, Wo, bo, (float*)d_out);
}